// Round 1
// baseline (975.729 us; speedup 1.0000x reference)
//
#include <hip/hip_runtime.h>

#define SQ 2048
#define HD 1024
#define NB 8
#define NTOT (NB*SQ)

typedef __bf16 bf16x8 __attribute__((ext_vector_type(8)));
typedef float f32x4 __attribute__((ext_vector_type(4)));
typedef short s16x8 __attribute__((ext_vector_type(8)));

__device__ __forceinline__ unsigned short f2bf(float x){
  unsigned u = __float_as_uint(x);
  return (unsigned short)((u + 0x7FFFu + ((u >> 16) & 1u)) >> 16);
}
__device__ __forceinline__ float bf2f(unsigned short h){
  return __uint_as_float(((unsigned)h) << 16);
}
// swizzled LDS index (shorts); applies on 8-short (16B) granules
__device__ __forceinline__ int swz(int r, int kshort){
  return (r * 32 + kshort) ^ ((r & 7) << 3);
}

__device__ __forceinline__ void load16f(const float* p, float* f){
  *(float4*)(f + 0)  = *(const float4*)(p + 0);
  *(float4*)(f + 4)  = *(const float4*)(p + 4);
  *(float4*)(f + 8)  = *(const float4*)(p + 8);
  *(float4*)(f + 12) = *(const float4*)(p + 12);
}

__device__ __forceinline__ void split_store16(const float* f, short* sh, short* sl,
                                              int i0, int i1){
  s16x8 h0, h1, l0, l1;
  #pragma unroll
  for (int j = 0; j < 8; j++){
    unsigned short a = f2bf(f[j]);
    h0[j] = (short)a;
    l0[j] = (short)f2bf(f[j] - bf2f(a));
    unsigned short b = f2bf(f[j + 8]);
    h1[j] = (short)b;
    l1[j] = (short)f2bf(f[j + 8] - bf2f(b));
  }
  *(s16x8*)&sh[i0] = h0;  *(s16x8*)&sh[i1] = h1;
  *(s16x8*)&sl[i0] = l0;  *(s16x8*)&sl[i1] = l1;
}

// C[M,N] = A[M,K] * B[N,K]^T (+bias), fp32 in/out, internally bf16 hi/lo 3-MFMA.
// C base selected per blockIdx.z from {C0,C1,C2} (for z>=2 uses C2+z*sC; pass
// C0==C1==C2 when sC!=0). causal: skip tiles with colTile > rowTile.
__global__ __launch_bounds__(256)
void gemm_nt_split3(const float* __restrict__ A, const float* __restrict__ B,
                    float* __restrict__ C0, float* __restrict__ C1, float* __restrict__ C2,
                    const float* __restrict__ b0, const float* __restrict__ b1,
                    const float* __restrict__ b2,
                    int K, long long sA, long long sB, long long sC,
                    int lda, int ldb, int ldc, int causal)
{
  if (causal && blockIdx.y > blockIdx.x) return;
  const int z = blockIdx.z;
  A += (long long)z * sA;
  B += (long long)z * sB;
  float* C = ((z == 0) ? C0 : (z == 1) ? C1 : C2) + (long long)z * sC;
  const float* bias = (z == 0) ? b0 : (z == 1) ? b1 : b2;

  __shared__ short sAh[128*32], sAl[128*32], sBh[128*32], sBl[128*32];

  const int tid  = threadIdx.x;
  const int lane = tid & 63, wid = tid >> 6;
  const int wm = wid >> 1, wn = wid & 1;
  const int lrow = lane & 15, kgrp = lane >> 4;

  const long long rowA = (long long)blockIdx.x * 128;
  const long long rowB = (long long)blockIdx.y * 128;

  const int sr = tid >> 1;
  const int skk = (tid & 1) << 4;
  const float* pA = A + (rowA + sr) * lda + skk;
  const float* pB = B + (rowB + sr) * ldb + skk;
  const int w0 = swz(sr, skk), w1 = swz(sr, skk + 8);

  alignas(16) float fa[16], fb[16];
  load16f(pA, fa);
  load16f(pB, fb);

  f32x4 acc[4][4];
  const f32x4 zf = {0.f, 0.f, 0.f, 0.f};
  #pragma unroll
  for (int m = 0; m < 4; m++)
    #pragma unroll
    for (int n = 0; n < 4; n++) acc[m][n] = zf;

  const int KT = K >> 5;
  for (int kt = 0; kt < KT; ++kt){
    __syncthreads();
    split_store16(fa, sAh, sAl, w0, w1);
    split_store16(fb, sBh, sBl, w0, w1);
    __syncthreads();
    pA += 32; pB += 32;
    if (kt + 1 < KT){ load16f(pA, fa); load16f(pB, fb); }

    bf16x8 ah[4], al[4];
    #pragma unroll
    for (int m = 0; m < 4; m++){
      int idx = swz(wm*64 + m*16 + lrow, kgrp*8);
      ah[m] = *(const bf16x8*)&sAh[idx];
      al[m] = *(const bf16x8*)&sAl[idx];
    }
    #pragma unroll
    for (int n = 0; n < 4; n++){
      int idx = swz(wn*64 + n*16 + lrow, kgrp*8);
      bf16x8 bh = *(const bf16x8*)&sBh[idx];
      bf16x8 bl = *(const bf16x8*)&sBl[idx];
      #pragma unroll
      for (int m = 0; m < 4; m++){
        acc[m][n] = __builtin_amdgcn_mfma_f32_16x16x32_bf16(ah[m], bh, acc[m][n], 0, 0, 0);
        acc[m][n] = __builtin_amdgcn_mfma_f32_16x16x32_bf16(al[m], bh, acc[m][n], 0, 0, 0);
        acc[m][n] = __builtin_amdgcn_mfma_f32_16x16x32_bf16(ah[m], bl, acc[m][n], 0, 0, 0);
      }
    }
  }

  #pragma unroll
  for (int n = 0; n < 4; n++){
    int col = (int)rowB + wn*64 + n*16 + lrow;
    float badd = bias ? bias[col] : 0.f;
    #pragma unroll
    for (int m = 0; m < 4; m++){
      long long r0 = rowA + wm*64 + m*16 + kgrp*4;
      #pragma unroll
      for (int j = 0; j < 4; j++)
        C[(r0 + j) * ldc + col] = acc[m][n][j] + badd;
    }
  }
}

// attn = P[S,S](bf16) * Vt[H,S](bf16)^T ; out = attn + Vf ; causal K-trim.
__global__ __launch_bounds__(256)
void gemm_pv(const unsigned short* __restrict__ Pm, const unsigned short* __restrict__ Vt,
             const float* __restrict__ Vf, float* __restrict__ Out,
             long long sP, long long sVt, long long sV, long long sO)
{
  const int z = blockIdx.z;
  Pm  += (long long)z * sP;
  Vt  += (long long)z * sVt;
  Vf  += (long long)z * sV;
  Out += (long long)z * sO;

  __shared__ short sA[128*32], sB[128*32];

  const int tid  = threadIdx.x;
  const int lane = tid & 63, wid = tid >> 6;
  const int wm = wid >> 1, wn = wid & 1;
  const int lrow = lane & 15, kgrp = lane >> 4;

  const long long rowA = (long long)blockIdx.x * 128;  // s rows
  const long long rowB = (long long)blockIdx.y * 128;  // h rows

  const int sr = tid >> 1;
  const int skk = (tid & 1) << 4;
  const unsigned short* pA = Pm + (rowA + sr) * SQ + skk;
  const unsigned short* pB = Vt + (rowB + sr) * SQ + skk;
  const int w0 = swz(sr, skk), w1 = swz(sr, skk + 8);

  s16x8 ra0 = *(const s16x8*)(pA), ra1 = *(const s16x8*)(pA + 8);
  s16x8 rb0 = *(const s16x8*)(pB), rb1 = *(const s16x8*)(pB + 8);

  f32x4 acc[4][4];
  const f32x4 zf = {0.f, 0.f, 0.f, 0.f};
  #pragma unroll
  for (int m = 0; m < 4; m++)
    #pragma unroll
    for (int n = 0; n < 4; n++) acc[m][n] = zf;

  const int KT = ((int)blockIdx.x + 1) * 4;  // keys <= (i+1)*128 ; P is 0 above diag
  for (int kt = 0; kt < KT; ++kt){
    __syncthreads();
    *(s16x8*)&sA[w0] = ra0;  *(s16x8*)&sA[w1] = ra1;
    *(s16x8*)&sB[w0] = rb0;  *(s16x8*)&sB[w1] = rb1;
    __syncthreads();
    pA += 32; pB += 32;
    if (kt + 1 < KT){
      ra0 = *(const s16x8*)(pA); ra1 = *(const s16x8*)(pA + 8);
      rb0 = *(const s16x8*)(pB); rb1 = *(const s16x8*)(pB + 8);
    }
    bf16x8 am[4];
    #pragma unroll
    for (int m = 0; m < 4; m++){
      int idx = swz(wm*64 + m*16 + lrow, kgrp*8);
      am[m] = *(const bf16x8*)&sA[idx];
    }
    #pragma unroll
    for (int n = 0; n < 4; n++){
      int idx = swz(wn*64 + n*16 + lrow, kgrp*8);
      bf16x8 bn = *(const bf16x8*)&sB[idx];
      #pragma unroll
      for (int m = 0; m < 4; m++)
        acc[m][n] = __builtin_amdgcn_mfma_f32_16x16x32_bf16(am[m], bn, acc[m][n], 0, 0, 0);
    }
  }

  #pragma unroll
  for (int n = 0; n < 4; n++){
    int col = (int)rowB + wn*64 + n*16 + lrow;
    #pragma unroll
    for (int m = 0; m < 4; m++){
      long long r0 = rowA + wm*64 + m*16 + kgrp*4;
      #pragma unroll
      for (int j = 0; j < 4; j++){
        long long o = (r0 + j) * HD + col;
        Out[o] = acc[m][n][j] + Vf[o];   // read-then-write same addr (Vf may alias Out)
      }
    }
  }
}

__global__ void transpose_w(const float* __restrict__ Wq, const float* __restrict__ Wk,
                            const float* __restrict__ Wv, float* __restrict__ Wt)
{
  __shared__ float t[32][33];
  const float* Win = (blockIdx.z == 0) ? Wq : (blockIdx.z == 1) ? Wk : Wv;
  float* Wo = Wt + (size_t)blockIdx.z * HD * HD;
  int n0 = blockIdx.x * 32, k0 = blockIdx.y * 32;
  int tx = threadIdx.x, ty = threadIdx.y;
  #pragma unroll
  for (int i = 0; i < 4; i++)
    t[ty + 8*i][tx] = Win[(size_t)(k0 + ty + 8*i) * HD + n0 + tx];
  __syncthreads();
  #pragma unroll
  for (int i = 0; i < 4; i++)
    Wo[(size_t)(n0 + ty + 8*i) * HD + k0 + tx] = t[tx][ty + 8*i];
}

__global__ void transpose_v(const float* __restrict__ V, unsigned short* __restrict__ Vt)
{
  __shared__ float t[32][33];
  int b = blockIdx.z;
  int s0 = blockIdx.x * 32, h0 = blockIdx.y * 32;
  int tx = threadIdx.x, ty = threadIdx.y;
  const float* Vb = V + (size_t)b * SQ * HD;
  unsigned short* Vo = Vt + (size_t)b * HD * SQ;
  #pragma unroll
  for (int i = 0; i < 4; i++)
    t[ty + 8*i][tx] = Vb[(size_t)(s0 + ty + 8*i) * HD + h0 + tx];
  __syncthreads();
  #pragma unroll
  for (int i = 0; i < 4; i++)
    Vo[(size_t)(h0 + ty + 8*i) * SQ + s0 + tx] = f2bf(t[tx][ty + 8*i]);
}

__global__ __launch_bounds__(256)
void softmax_causal(const float* __restrict__ SC, unsigned short* __restrict__ P)
{
  const int s = blockIdx.x;
  const long long zoff = (long long)blockIdx.y * SQ * SQ;
  const float* row = SC + zoff + (long long)s * SQ;
  unsigned short* prow = P + zoff + (long long)s * SQ;

  __shared__ float buf[SQ];
  __shared__ float red[4];
  const int tid = threadIdx.x, lane = tid & 63, wid = tid >> 6;

  float m = -3.4e38f;
  for (int t = tid; t <= s; t += 256){ float v = row[t]; buf[t] = v; m = fmaxf(m, v); }
  #pragma unroll
  for (int o = 32; o; o >>= 1) m = fmaxf(m, __shfl_xor(m, o));
  if (lane == 0) red[wid] = m;
  __syncthreads();
  m = fmaxf(fmaxf(red[0], red[1]), fmaxf(red[2], red[3]));
  __syncthreads();

  float sum = 0.f;
  for (int t = tid; t <= s; t += 256){ float e = __expf(buf[t] - m); buf[t] = e; sum += e; }
  #pragma unroll
  for (int o = 32; o; o >>= 1) sum += __shfl_xor(sum, o);
  if (lane == 0) red[wid] = sum;
  __syncthreads();
  sum = red[0] + red[1] + red[2] + red[3];
  const float inv = 1.f / sum;

  for (int t = tid; t < SQ; t += 256)
    prow[t] = (t <= s) ? f2bf(buf[t] * inv) : (unsigned short)0;
}

__global__ __launch_bounds__(256)
void layernorm_inplace(float* __restrict__ Y, const float* __restrict__ gamma,
                       const float* __restrict__ beta)
{
  float* y = Y + (long long)blockIdx.x * HD;
  const int tid = threadIdx.x, lane = tid & 63, wid = tid >> 6;
  float xv[4];
  float s = 0.f, ss = 0.f;
  #pragma unroll
  for (int i = 0; i < 4; i++){
    float v = y[tid + i * 256];
    xv[i] = v; s += v; ss += v * v;
  }
  #pragma unroll
  for (int o = 32; o; o >>= 1){ s += __shfl_xor(s, o); ss += __shfl_xor(ss, o); }
  __shared__ float r1[4], r2[4];
  if (lane == 0){ r1[wid] = s; r2[wid] = ss; }
  __syncthreads();
  s  = r1[0] + r1[1] + r1[2] + r1[3];
  ss = r2[0] + r2[1] + r2[2] + r2[3];
  const float mu   = s * (1.f / HD);
  const float var  = ss * (1.f / HD) - mu * mu;
  const float rstd = rsqrtf(var + 1e-5f);
  #pragma unroll
  for (int i = 0; i < 4; i++){
    int c = tid + i * 256;
    y[c] = (xv[i] - mu) * rstd * gamma[c] + beta[c];
  }
}

extern "C" void kernel_launch(void* const* d_in, const int* in_sizes, int n_in,
                              void* d_out, int out_size, void* d_ws, size_t ws_size,
                              hipStream_t stream)
{
  const float* x     = (const float*)d_in[0];
  const float* Wq    = (const float*)d_in[1];
  const float* bq    = (const float*)d_in[2];
  const float* Wk    = (const float*)d_in[3];
  const float* bk    = (const float*)d_in[4];
  const float* Wv    = (const float*)d_in[5];
  const float* bv    = (const float*)d_in[6];
  const float* gamma = (const float*)d_in[7];
  const float* beta  = (const float*)d_in[8];
  float* out = (float*)d_out;

  // workspace carve-up (256B aligned). V lives in d_out to save 67 MB.
  char* w = (char*)d_ws;
  size_t off = 0;
  auto alloc = [&](size_t bytes) -> char* {
    char* p = w + off;
    off = (off + bytes + 255) & ~(size_t)255;
    return p;
  };
  float*          Wt = (float*)alloc(3ULL * HD * HD * 4);              // 12.6 MB
  float*          Q  = (float*)alloc((size_t)NTOT * HD * 4);           // 67 MB
  float*          Kb = (float*)alloc((size_t)NTOT * HD * 4);           // 67 MB
  unsigned short* Vt = (unsigned short*)alloc((size_t)NB * HD * SQ * 2); // 33.5 MB
  size_t rem = (ws_size > off) ? (ws_size - off) : 0;
  int G = (int)(rem / ((size_t)SQ * SQ * 6));
  if (G > NB) G = NB;
  if (G < 1)  G = 1;            // needs >= ~206 MB total workspace
  float*          SC = (float*)alloc((size_t)G * SQ * SQ * 4);
  unsigned short* P  = (unsigned short*)alloc((size_t)G * SQ * SQ * 2);

  float* V = out;  // V stored in d_out; PV epilogue reads V[o] then overwrites o

  transpose_w<<<dim3(HD/32, HD/32, 3), dim3(32, 8), 0, stream>>>(Wq, Wk, Wv, Wt);

  // QKV: A=x, B=Wt[z], C in {Q, K, out(V)}, +bias
  gemm_nt_split3<<<dim3(NTOT/128, HD/128, 3), 256, 0, stream>>>(
      x, Wt, Q, Kb, V, bq, bk, bv,
      HD, 0LL, (long long)HD * HD, 0LL,
      HD, HD, HD, 0);

  transpose_v<<<dim3(SQ/32, HD/32, NB), dim3(32, 8), 0, stream>>>(V, Vt);

  for (int g0 = 0; g0 < NB; g0 += G){
    int g = (G < NB - g0) ? G : (NB - g0);
    gemm_nt_split3<<<dim3(SQ/128, SQ/128, g), 256, 0, stream>>>(
        Q + (size_t)g0 * SQ * HD, Kb + (size_t)g0 * SQ * HD,
        SC, SC, SC, nullptr, nullptr, nullptr,
        HD, (long long)SQ * HD, (long long)SQ * HD, (long long)SQ * SQ,
        HD, HD, SQ, 1);
    softmax_causal<<<dim3(SQ, g), 256, 0, stream>>>(SC, P);
    gemm_pv<<<dim3(SQ/128, HD/128, g), 256, 0, stream>>>(
        P, Vt + (size_t)g0 * HD * SQ,
        V + (size_t)g0 * SQ * HD, out + (size_t)g0 * SQ * HD,
        (long long)SQ * SQ, (long long)HD * SQ,
        (long long)SQ * HD, (long long)SQ * HD);
  }

  layernorm_inplace<<<dim3(NTOT), 256, 0, stream>>>(out, gamma, beta);
}

// Round 2
// 855.733 us; speedup vs baseline: 1.1402x; 1.1402x over previous
//
#include <hip/hip_runtime.h>

#define SQ 2048
#define HD 1024
#define NB 8
#define NTOT (NB*SQ)

typedef __bf16 bf16x8 __attribute__((ext_vector_type(8)));
typedef float f32x4 __attribute__((ext_vector_type(4)));
typedef short s16x8 __attribute__((ext_vector_type(8)));
typedef unsigned short u16;

__device__ __forceinline__ u16 f2bf(float x){
  unsigned u = __float_as_uint(x);
  return (u16)((u + 0x7FFFu + ((u >> 16) & 1u)) >> 16);
}
__device__ __forceinline__ float bf2f(u16 h){
  return __uint_as_float(((unsigned)h) << 16);
}

// async global->LDS, 16B per lane; LDS dest = wave-uniform base + lane*16
#define STG(gp, lp) __builtin_amdgcn_global_load_lds( \
    (const __attribute__((address_space(1))) unsigned*)(gp), \
    (__attribute__((address_space(3))) unsigned*)(lp), 16, 0, 0)

// ---------------------------------------------------------------------------
// Unified 128x128 bf16 MFMA GEMM, C = A[M,K] * B[N,K]^T (NT form).
// Operands pre-split into hi/lo bf16 planes (NSPLIT==3: 3-MFMA split product).
// Staging via global_load_lds with granule-XOR swizzle: LDS 16B-granule
// q = 4r + (kq ^ (r&3)) holds global (row r, k-quad kq). Reads then hit a
// bijective 1KiB sweep per wave instruction (<=2-way bank aliasing, free).
// EPI: 0 = split-bf16 out (+bias)  [QKV->Q,K]
//      1 = fp32 out (+bias)        [QKV->V]
//      2 = fp32 out, causal tile skip  [scores]
//      3 = fp32 out + residual, K-trimmed by row tile  [PV]
// ---------------------------------------------------------------------------
template<int NSPLIT, int EPI>
__global__ __launch_bounds__(256)
void gemm_tile(const u16* __restrict__ Ah, const u16* __restrict__ Al,
               const u16* __restrict__ Bh, const u16* __restrict__ Bl,
               float* Cf, u16* Ch, u16* Cl,
               const float* __restrict__ b0, const float* __restrict__ b1,
               const float* resid,
               int K, int lda, int ldb, int ldc,
               long long sA, long long sB, long long sC, int causal)
{
  if (EPI == 2 && causal && blockIdx.y > blockIdx.x) return;
  const int z = blockIdx.z;
  Ah += z * sA; Bh += z * sB;
  if (NSPLIT == 3){ Al += z * sA; Bl += z * sB; }

  constexpr int LDSW = (NSPLIT == 3) ? 4 * 4096 : 2 * 4096;
  __shared__ short lds[LDSW];   // tiles: [Ah, Bh, (Al, Bl)] each 128x32 shorts

  const int tid  = threadIdx.x;
  const int lane = tid & 63, w = tid >> 6;
  const int wm = w >> 1, wn = w & 1;
  const int lrow = lane & 15, kgrp = lane >> 4;

  const long long rowA = (long long)blockIdx.x * 128;
  const long long rowB = (long long)blockIdx.y * 128;

  // --- staging: 2 granules (16B) per thread per tile ---
  const int q0 = w * 128 + lane, q1 = q0 + 64;
  const int r0s = q0 >> 2, r1s = q1 >> 2;
  const int kq0 = (q0 & 3) ^ (r0s & 3), kq1 = (q1 & 3) ^ (r1s & 3);

  const long long oA0 = (rowA + r0s) * (long long)lda + (kq0 << 3);
  const long long oA1 = (rowA + r1s) * (long long)lda + (kq1 << 3);
  const long long oB0 = (rowB + r0s) * (long long)ldb + (kq0 << 3);
  const long long oB1 = (rowB + r1s) * (long long)ldb + (kq1 << 3);
  const u16 *gAh0 = Ah + oA0, *gAh1 = Ah + oA1;
  const u16 *gBh0 = Bh + oB0, *gBh1 = Bh + oB1;
  const u16 *gAl0 = Ah, *gAl1 = Ah, *gBl0 = Bh, *gBl1 = Bh;
  if (NSPLIT == 3){ gAl0 = Al + oA0; gAl1 = Al + oA1; gBl0 = Bl + oB0; gBl1 = Bl + oB1; }

  short* lA0 = lds + 0*4096 + (w*2+0)*512;
  short* lA1 = lds + 0*4096 + (w*2+1)*512;
  short* lB0 = lds + 1*4096 + (w*2+0)*512;
  short* lB1 = lds + 1*4096 + (w*2+1)*512;
  short* lAl0 = lds, *lAl1 = lds, *lBl0 = lds, *lBl1 = lds;
  if (NSPLIT == 3){
    lAl0 = lds + 2*4096 + (w*2+0)*512;  lAl1 = lds + 2*4096 + (w*2+1)*512;
    lBl0 = lds + 3*4096 + (w*2+0)*512;  lBl1 = lds + 3*4096 + (w*2+1)*512;
  }

  // --- fragment read bases (swizzle-matched) ---
  const int kqr8 = ((kgrp ^ (lrow & 3)) << 3);
  const short* rdA  = lds + 0*4096 + ((wm*64 + lrow) << 5) + kqr8;   // + m*512
  const short* rdB  = lds + 1*4096 + ((wn*64 + lrow) << 5) + kqr8;   // + n*512
  const short* rdAl = lds + 2*4096 + ((wm*64 + lrow) << 5) + kqr8;
  const short* rdBl = lds + 3*4096 + ((wn*64 + lrow) << 5) + kqr8;

  f32x4 acc[4][4];
  const f32x4 zf = {0.f, 0.f, 0.f, 0.f};
  #pragma unroll
  for (int m = 0; m < 4; m++)
    #pragma unroll
    for (int n = 0; n < 4; n++) acc[m][n] = zf;

  int KT = K >> 5;
  if (EPI == 3){ int t = ((int)blockIdx.x + 1) * 4; if (t < KT) KT = t; }

  for (int kt = 0; kt < KT; ++kt){
    __syncthreads();                       // prev-tile readers done
    STG(gAh0, lA0);  STG(gAh1, lA1);
    STG(gBh0, lB0);  STG(gBh1, lB1);
    if (NSPLIT == 3){
      STG(gAl0, lAl0);  STG(gAl1, lAl1);
      STG(gBl0, lBl0);  STG(gBl1, lBl1);
    }
    gAh0 += 32; gAh1 += 32; gBh0 += 32; gBh1 += 32;
    if (NSPLIT == 3){ gAl0 += 32; gAl1 += 32; gBl0 += 32; gBl1 += 32; }
    __syncthreads();                       // includes vmcnt(0) drain

    bf16x8 ah[4], al[4];
    #pragma unroll
    for (int m = 0; m < 4; m++){
      ah[m] = *(const bf16x8*)(rdA + m*512);
      if (NSPLIT == 3) al[m] = *(const bf16x8*)(rdAl + m*512);
    }
    #pragma unroll
    for (int n = 0; n < 4; n++){
      bf16x8 bh = *(const bf16x8*)(rdB + n*512);
      bf16x8 bl = bh;
      if (NSPLIT == 3) bl = *(const bf16x8*)(rdBl + n*512);
      #pragma unroll
      for (int m = 0; m < 4; m++){
        acc[m][n] = __builtin_amdgcn_mfma_f32_16x16x32_bf16(ah[m], bh, acc[m][n], 0, 0, 0);
        if (NSPLIT == 3){
          acc[m][n] = __builtin_amdgcn_mfma_f32_16x16x32_bf16(al[m], bh, acc[m][n], 0, 0, 0);
          acc[m][n] = __builtin_amdgcn_mfma_f32_16x16x32_bf16(ah[m], bl, acc[m][n], 0, 0, 0);
        }
      }
    }
  }

  // --- epilogue ---
  if (EPI == 0){
    u16* ch = Ch + z * sC;  u16* cl = Cl + z * sC;
    const float* bias = z ? b1 : b0;
    #pragma unroll
    for (int n = 0; n < 4; n++){
      int col = (int)rowB + wn*64 + n*16 + lrow;
      float ba = bias[col];
      #pragma unroll
      for (int m = 0; m < 4; m++){
        long long r = rowA + wm*64 + m*16 + kgrp*4;
        #pragma unroll
        for (int j = 0; j < 4; j++){
          float v = acc[m][n][j] + ba;
          u16 h = f2bf(v);
          long long o = (r + j) * ldc + col;
          ch[o] = h;  cl[o] = f2bf(v - bf2f(h));
        }
      }
    }
  } else if (EPI == 1){
    float* cf = Cf + z * sC;
    #pragma unroll
    for (int n = 0; n < 4; n++){
      int col = (int)rowB + wn*64 + n*16 + lrow;
      float ba = b0[col];
      #pragma unroll
      for (int m = 0; m < 4; m++){
        long long r = rowA + wm*64 + m*16 + kgrp*4;
        #pragma unroll
        for (int j = 0; j < 4; j++)
          cf[(r + j) * ldc + col] = acc[m][n][j] + ba;
      }
    }
  } else if (EPI == 2){
    float* cf = Cf + z * sC;
    #pragma unroll
    for (int n = 0; n < 4; n++){
      int col = (int)rowB + wn*64 + n*16 + lrow;
      #pragma unroll
      for (int m = 0; m < 4; m++){
        long long r = rowA + wm*64 + m*16 + kgrp*4;
        #pragma unroll
        for (int j = 0; j < 4; j++)
          cf[(r + j) * ldc + col] = acc[m][n][j];
      }
    }
  } else {
    float* cf = Cf + z * sC;
    const float* rs = resid + z * sC;
    #pragma unroll
    for (int n = 0; n < 4; n++){
      int col = (int)rowB + wn*64 + n*16 + lrow;
      #pragma unroll
      for (int m = 0; m < 4; m++){
        long long r = rowA + wm*64 + m*16 + kgrp*4;
        #pragma unroll
        for (int j = 0; j < 4; j++){
          long long o = (r + j) * ldc + col;
          cf[o] = acc[m][n][j] + rs[o];    // rs may alias cf at same addr only
        }
      }
    }
  }
}

// x fp32 -> hi/lo bf16 planes
__global__ __launch_bounds__(256)
void prep_x(const float* __restrict__ X, u16* __restrict__ Xh, u16* __restrict__ Xl)
{
  const long long n8 = (long long)NTOT * HD / 8;
  for (long long i = (long long)blockIdx.x * 256 + threadIdx.x; i < n8;
       i += (long long)gridDim.x * 256){
    const float* p = X + i * 8;
    float4 a = *(const float4*)p;
    float4 b = *(const float4*)(p + 4);
    float f[8] = {a.x, a.y, a.z, a.w, b.x, b.y, b.z, b.w};
    s16x8 h, l;
    #pragma unroll
    for (int j = 0; j < 8; j++){
      u16 hh = f2bf(f[j]);
      h[j] = (short)hh;
      l[j] = (short)f2bf(f[j] - bf2f(hh));
    }
    *(s16x8*)&Xh[i * 8] = h;
    *(s16x8*)&Xl[i * 8] = l;
  }
}

// W[k][n] -> transposed hi/lo bf16 planes Wt[z][n][k]
__global__ void prep_w(const float* __restrict__ Wq, const float* __restrict__ Wk,
                       const float* __restrict__ Wv,
                       u16* __restrict__ Wth, u16* __restrict__ Wtl)
{
  __shared__ float t[32][33];
  const float* Win = (blockIdx.z == 0) ? Wq : (blockIdx.z == 1) ? Wk : Wv;
  const size_t zo = (size_t)blockIdx.z * HD * HD;
  int n0 = blockIdx.x * 32, k0 = blockIdx.y * 32;
  int tx = threadIdx.x, ty = threadIdx.y;
  #pragma unroll
  for (int i = 0; i < 4; i++)
    t[ty + 8*i][tx] = Win[(size_t)(k0 + ty + 8*i) * HD + n0 + tx];
  __syncthreads();
  #pragma unroll
  for (int i = 0; i < 4; i++){
    float v = t[tx][ty + 8*i];
    u16 h = f2bf(v);
    size_t o = zo + (size_t)(n0 + ty + 8*i) * HD + k0 + tx;
    Wth[o] = h;
    Wtl[o] = f2bf(v - bf2f(h));
  }
}

// V fp32 [S,H] per batch -> Vt bf16 [H,S]
__global__ void transpose_v(const float* __restrict__ V, u16* __restrict__ Vt)
{
  __shared__ float t[32][33];
  int b = blockIdx.z;
  int s0 = blockIdx.x * 32, h0 = blockIdx.y * 32;
  int tx = threadIdx.x, ty = threadIdx.y;
  const float* Vb = V + (size_t)b * SQ * HD;
  u16* Vo = Vt + (size_t)b * HD * SQ;
  #pragma unroll
  for (int i = 0; i < 4; i++)
    t[ty + 8*i][tx] = Vb[(size_t)(s0 + ty + 8*i) * HD + h0 + tx];
  __syncthreads();
  #pragma unroll
  for (int i = 0; i < 4; i++)
    Vo[(size_t)(h0 + ty + 8*i) * SQ + s0 + tx] = f2bf(t[tx][ty + 8*i]);
}

__global__ __launch_bounds__(256)
void softmax_causal(const float* __restrict__ SC, u16* __restrict__ P)
{
  const int s = blockIdx.x;
  const long long zoff = (long long)blockIdx.y * SQ * SQ;
  const float* row = SC + zoff + (long long)s * SQ;
  u16* prow = P + zoff + (long long)s * SQ;

  __shared__ float buf[SQ];
  __shared__ float red[4];
  const int tid = threadIdx.x, lane = tid & 63, wid = tid >> 6;

  float m = -3.4e38f;
  for (int t = tid; t <= s; t += 256){ float v = row[t]; buf[t] = v; m = fmaxf(m, v); }
  #pragma unroll
  for (int o = 32; o; o >>= 1) m = fmaxf(m, __shfl_xor(m, o));
  if (lane == 0) red[wid] = m;
  __syncthreads();
  m = fmaxf(fmaxf(red[0], red[1]), fmaxf(red[2], red[3]));
  __syncthreads();

  float sum = 0.f;
  for (int t = tid; t <= s; t += 256){ float e = __expf(buf[t] - m); buf[t] = e; sum += e; }
  #pragma unroll
  for (int o = 32; o; o >>= 1) sum += __shfl_xor(sum, o);
  if (lane == 0) red[wid] = sum;
  __syncthreads();
  sum = red[0] + red[1] + red[2] + red[3];
  const float inv = 1.f / sum;

  const int lim = ((s >> 7) + 1) << 7;   // PV only reads keys < ceil128(s+1)
  for (int t = tid; t < lim; t += 256)
    prow[t] = (t <= s) ? f2bf(buf[t] * inv) : (u16)0;
}

__global__ __launch_bounds__(256)
void layernorm_inplace(float* __restrict__ Y, const float* __restrict__ gamma,
                       const float* __restrict__ beta)
{
  float* y = Y + (long long)blockIdx.x * HD;
  const int tid = threadIdx.x, lane = tid & 63, wid = tid >> 6;
  float xv[4];
  float s = 0.f, ss = 0.f;
  #pragma unroll
  for (int i = 0; i < 4; i++){
    float v = y[tid + i * 256];
    xv[i] = v; s += v; ss += v * v;
  }
  #pragma unroll
  for (int o = 32; o; o >>= 1){ s += __shfl_xor(s, o); ss += __shfl_xor(ss, o); }
  __shared__ float r1[4], r2[4];
  if (lane == 0){ r1[wid] = s; r2[wid] = ss; }
  __syncthreads();
  s  = r1[0] + r1[1] + r1[2] + r1[3];
  ss = r2[0] + r2[1] + r2[2] + r2[3];
  const float mu   = s * (1.f / HD);
  const float var  = ss * (1.f / HD) - mu * mu;
  const float rstd = rsqrtf(var + 1e-5f);
  #pragma unroll
  for (int i = 0; i < 4; i++){
    int c = tid + i * 256;
    y[c] = (xv[i] - mu) * rstd * gamma[c] + beta[c];
  }
}

extern "C" void kernel_launch(void* const* d_in, const int* in_sizes, int n_in,
                              void* d_out, int out_size, void* d_ws, size_t ws_size,
                              hipStream_t stream)
{
  const float* x     = (const float*)d_in[0];
  const float* Wq    = (const float*)d_in[1];
  const float* bq    = (const float*)d_in[2];
  const float* Wk    = (const float*)d_in[3];
  const float* bk    = (const float*)d_in[4];
  const float* Wv    = (const float*)d_in[5];
  const float* bv    = (const float*)d_in[6];
  const float* gamma = (const float*)d_in[7];
  const float* beta  = (const float*)d_in[8];
  float* out = (float*)d_out;

  char* wsp = (char*)d_ws;
  size_t off = 0;
  auto alloc = [&](size_t bytes) -> char* {
    char* p = wsp + off;
    off = (off + bytes + 255) & ~(size_t)255;
    return p;
  };

  u16* Wth = (u16*)alloc(3ULL * HD * HD * 2);         // 6.3 MB
  u16* Wtl = (u16*)alloc(3ULL * HD * HD * 2);         // 6.3 MB
  u16* QKh = (u16*)alloc(2ULL * NTOT * HD * 2);       // 67.1 MB  (Q plane, K plane)
  u16* QKl = (u16*)alloc(2ULL * NTOT * HD * 2);       // 67.1 MB
  u16* Vt  = (u16*)alloc((size_t)NB * HD * SQ * 2);   // 33.6 MB

  // region4: xh/xl (phase A) aliased with SC/P (phase B); both dead across phases
  size_t rem = (ws_size > off) ? (ws_size - off) : 0;
  int G = (int)(rem / ((size_t)SQ * SQ * 6));
  if (G > NB) G = NB;
  if (G < 1)  G = 1;
  u16*   xh = (u16*)(wsp + off);
  u16*   xl = xh + (size_t)NTOT * HD;                 // 67.1 MB total
  float* SC = (float*)(wsp + off);                    // G * 16.8 MB
  u16*   P  = (u16*)(wsp + off + (size_t)G * SQ * SQ * 4);  // G * 8.4 MB

  u16* Qh = QKh;                     u16* Ql = QKl;
  u16* Kh = QKh + (size_t)NTOT * HD; u16* Kl = QKl + (size_t)NTOT * HD;
  float* V = out;   // V lives in d_out; PV reads V[o] then overwrites o

  prep_x<<<dim3(2048), dim3(256), 0, stream>>>(x, xh, xl);
  prep_w<<<dim3(HD/32, HD/32, 3), dim3(32, 8), 0, stream>>>(Wq, Wk, Wv, Wth, Wtl);

  // Q,K projections: split3, split-bf16 output (+bias)
  gemm_tile<3, 0><<<dim3(NTOT/128, HD/128, 2), 256, 0, stream>>>(
      xh, xl, Wth, Wtl, nullptr, QKh, QKl, bq, bk, nullptr,
      HD, HD, HD, HD, 0LL, (long long)HD * HD, (long long)NTOT * HD, 0);

  // V projection: plain bf16 (hi planes), fp32 out (+bias) into d_out
  gemm_tile<1, 1><<<dim3(NTOT/128, HD/128, 1), 256, 0, stream>>>(
      xh, nullptr, Wth + 2ULL * HD * HD, nullptr, V, nullptr, nullptr, bv, nullptr, nullptr,
      HD, HD, HD, HD, 0LL, 0LL, 0LL, 0);

  transpose_v<<<dim3(SQ/32, HD/32, NB), dim3(32, 8), 0, stream>>>(V, Vt);

  for (int g0 = 0; g0 < NB; g0 += G){
    int g = (G < NB - g0) ? G : (NB - g0);
    gemm_tile<3, 2><<<dim3(SQ/128, SQ/128, g), 256, 0, stream>>>(
        Qh + (size_t)g0 * SQ * HD, Ql + (size_t)g0 * SQ * HD,
        Kh + (size_t)g0 * SQ * HD, Kl + (size_t)g0 * SQ * HD,
        SC, nullptr, nullptr, nullptr, nullptr, nullptr,
        HD, HD, HD, SQ,
        (long long)SQ * HD, (long long)SQ * HD, (long long)SQ * SQ, 1);
    softmax_causal<<<dim3(SQ, g), 256, 0, stream>>>(SC, P);
    gemm_tile<1, 3><<<dim3(SQ/128, HD/128, g), 256, 0, stream>>>(
        P, nullptr, Vt + (size_t)g0 * HD * SQ, nullptr,
        out + (size_t)g0 * SQ * HD, nullptr, nullptr, nullptr, nullptr,
        out + (size_t)g0 * SQ * HD,
        SQ, SQ, SQ, HD,
        (long long)SQ * SQ, (long long)HD * SQ, (long long)SQ * HD, 0);
  }

  layernorm_inplace<<<dim3(NTOT), 256, 0, stream>>>(out, gamma, beta);
}

// Round 3
// 511.159 us; speedup vs baseline: 1.9089x; 1.6741x over previous
//
#include <hip/hip_runtime.h>

#define SQ 2048
#define HD 1024
#define NB 8
#define NTOT (NB*SQ)

typedef _Float16 f16x8 __attribute__((ext_vector_type(8)));
typedef float f32x4 __attribute__((ext_vector_type(4)));
typedef short s16x8 __attribute__((ext_vector_type(8)));
typedef unsigned short u16;

__device__ __forceinline__ u16 f2h(float x){
  _Float16 h = (_Float16)x;
  u16 u; __builtin_memcpy(&u, &h, 2); return u;
}

// async global->LDS, 16B per lane; LDS dest = wave-uniform base + lane*16
#define STG(gp, lp) __builtin_amdgcn_global_load_lds( \
    (const __attribute__((address_space(1))) unsigned*)(gp), \
    (__attribute__((address_space(3))) unsigned*)(lp), 16, 0, 0)

// ---------------------------------------------------------------------------
// Unified 128x128 f16 MFMA GEMM, C = A[M,K] * B[N,K]^T (NT form), fp32 accum.
// Staging via global_load_lds, granule-XOR swizzle (q = 4r + (kq ^ (r&3))).
// EPI 0: QKV projection. z=0:Q->f16, z=1:K->f16, z=2:V->fp32(d_out)+Vt f16[H,S]
// EPI 1: scores -> fp32, causal-compact triangular grid (blockIdx.x = tri idx)
// EPI 2: PV + residual -> fp32, K-trimmed by row tile
// ---------------------------------------------------------------------------
template<int EPI>
__global__ __launch_bounds__(256)
void gemm_f16(const u16* __restrict__ A, const u16* __restrict__ B,
              float* Cf, u16* Ch, u16* Vt,
              const float* __restrict__ b0, const float* __restrict__ b1,
              const float* __restrict__ b2,
              int K, int lda, int ldb, int ldc,
              long long sA, long long sB, long long sC)
{
  const int z = blockIdx.z;
  int bi = blockIdx.x, bj = blockIdx.y;
  if (EPI == 1){                       // triangular decode: t -> (i, j<=i)
    int t = bi;
    int i = (int)((sqrtf(8.f * (float)t + 1.f) - 1.f) * 0.5f);
    while ((i + 1) * (i + 2) / 2 <= t) ++i;
    while (i * (i + 1) / 2 > t) --i;
    bi = i;  bj = t - i * (i + 1) / 2;
  }

  A += (long long)z * sA;
  B += (long long)z * sB;

  __shared__ short lds[2 * 4096];      // A tile 128x32, B tile 128x32 (f16)

  const int tid  = threadIdx.x;
  const int lane = tid & 63, w = tid >> 6;
  const int wm = w >> 1, wn = w & 1;
  const int lrow = lane & 15, kgrp = lane >> 4;

  const long long rowA = (long long)bi * 128;
  const long long rowB = (long long)bj * 128;

  // staging: 4 granules (16B) per thread (2 for A, 2 for B)
  const int q0 = w * 128 + lane, q1 = q0 + 64;
  const int r0s = q0 >> 2, r1s = q1 >> 2;
  const int kq0 = (q0 & 3) ^ (r0s & 3), kq1 = (q1 & 3) ^ (r1s & 3);

  const u16* gA0 = A + (rowA + r0s) * (long long)lda + (kq0 << 3);
  const u16* gA1 = A + (rowA + r1s) * (long long)lda + (kq1 << 3);
  const u16* gB0 = B + (rowB + r0s) * (long long)ldb + (kq0 << 3);
  const u16* gB1 = B + (rowB + r1s) * (long long)ldb + (kq1 << 3);

  short* lA0 = lds + (w * 2 + 0) * 512;
  short* lA1 = lds + (w * 2 + 1) * 512;
  short* lB0 = lds + 4096 + (w * 2 + 0) * 512;
  short* lB1 = lds + 4096 + (w * 2 + 1) * 512;

  // fragment read bases (swizzle-matched)
  const int kqr8 = ((kgrp ^ (lrow & 3)) << 3);
  const short* rdA = lds +        ((wm * 64 + lrow) << 5) + kqr8;   // + m*512
  const short* rdB = lds + 4096 + ((wn * 64 + lrow) << 5) + kqr8;   // + n*512

  f32x4 acc[4][4];
  const f32x4 zf = {0.f, 0.f, 0.f, 0.f};
  #pragma unroll
  for (int m = 0; m < 4; m++)
    #pragma unroll
    for (int n = 0; n < 4; n++) acc[m][n] = zf;

  int KT = K >> 5;
  if (EPI == 2){ int t = (bi + 1) * 4; if (t < KT) KT = t; }

  for (int kt = 0; kt < KT; ++kt){
    __syncthreads();                   // prev-tile readers done
    STG(gA0, lA0);  STG(gA1, lA1);
    STG(gB0, lB0);  STG(gB1, lB1);
    gA0 += 32; gA1 += 32; gB0 += 32; gB1 += 32;
    __syncthreads();                   // includes vmcnt(0) drain

    f16x8 af[4];
    #pragma unroll
    for (int m = 0; m < 4; m++)
      af[m] = *(const f16x8*)(rdA + m * 512);
    #pragma unroll
    for (int n = 0; n < 4; n++){
      f16x8 bf = *(const f16x8*)(rdB + n * 512);
      #pragma unroll
      for (int m = 0; m < 4; m++)
        acc[m][n] = __builtin_amdgcn_mfma_f32_16x16x32_f16(af[m], bf, acc[m][n], 0, 0, 0);
    }
  }

  // ---- epilogues ----
  if (EPI == 0){
    if (z < 2){
      u16* c = Ch + (long long)z * sC;
      const float* bias = z ? b1 : b0;
      #pragma unroll
      for (int n = 0; n < 4; n++){
        int col = (int)rowB + wn * 64 + n * 16 + lrow;
        float ba = bias[col];
        #pragma unroll
        for (int m = 0; m < 4; m++){
          long long r = rowA + wm * 64 + m * 16 + kgrp * 4;
          #pragma unroll
          for (int j = 0; j < 4; j++)
            c[(r + j) * ldc + col] = f2h(acc[m][n][j] + ba);
        }
      }
    } else {
      // V: fp32 (+bias) into d_out, and transposed f16 into Vt[b][h][s]
      const int bb = (int)(rowA >> 11);
      u16* vtb = Vt + (long long)bb * HD * SQ;
      #pragma unroll
      for (int n = 0; n < 4; n++){
        int col = (int)rowB + wn * 64 + n * 16 + lrow;
        float ba = b2[col];
        u16* vtc = vtb + (long long)col * SQ;
        #pragma unroll
        for (int m = 0; m < 4; m++){
          long long r = rowA + wm * 64 + m * 16 + kgrp * 4;
          int s = (int)(r & 2047);
          #pragma unroll
          for (int j = 0; j < 4; j++){
            float v = acc[m][n][j] + ba;
            Cf[(r + j) * ldc + col] = v;
            vtc[s + j] = f2h(v);
          }
        }
      }
    }
  } else if (EPI == 1){
    float* cf = Cf + (long long)z * sC;
    #pragma unroll
    for (int n = 0; n < 4; n++){
      int col = (int)rowB + wn * 64 + n * 16 + lrow;
      #pragma unroll
      for (int m = 0; m < 4; m++){
        long long r = rowA + wm * 64 + m * 16 + kgrp * 4;
        #pragma unroll
        for (int j = 0; j < 4; j++)
          cf[(r + j) * ldc + col] = acc[m][n][j];
      }
    }
  } else {
    float* cf = Cf + (long long)z * sC;
    #pragma unroll
    for (int n = 0; n < 4; n++){
      int col = (int)rowB + wn * 64 + n * 16 + lrow;
      #pragma unroll
      for (int m = 0; m < 4; m++){
        long long r = rowA + wm * 64 + m * 16 + kgrp * 4;
        #pragma unroll
        for (int j = 0; j < 4; j++){
          long long o = (r + j) * ldc + col;
          cf[o] = acc[m][n][j] + cf[o];   // residual: read V then overwrite
        }
      }
    }
  }
}

// x fp32 -> f16 plane
__global__ __launch_bounds__(256)
void prep_x(const float* __restrict__ X, u16* __restrict__ Xh)
{
  const long long n8 = (long long)NTOT * HD / 8;
  for (long long i = (long long)blockIdx.x * 256 + threadIdx.x; i < n8;
       i += (long long)gridDim.x * 256){
    const float* p = X + i * 8;
    float4 a = *(const float4*)p;
    float4 b = *(const float4*)(p + 4);
    float f[8] = {a.x, a.y, a.z, a.w, b.x, b.y, b.z, b.w};
    s16x8 h;
    #pragma unroll
    for (int j = 0; j < 8; j++) h[j] = (short)f2h(f[j]);
    *(s16x8*)&Xh[i * 8] = h;
  }
}

// W[k][n] -> transposed f16 Wt[z][n][k]
__global__ void prep_w(const float* __restrict__ Wq, const float* __restrict__ Wk,
                       const float* __restrict__ Wv, u16* __restrict__ Wt)
{
  __shared__ float t[32][33];
  const float* Win = (blockIdx.z == 0) ? Wq : (blockIdx.z == 1) ? Wk : Wv;
  const size_t zo = (size_t)blockIdx.z * HD * HD;
  int n0 = blockIdx.x * 32, k0 = blockIdx.y * 32;
  int tx = threadIdx.x, ty = threadIdx.y;
  #pragma unroll
  for (int i = 0; i < 4; i++)
    t[ty + 8*i][tx] = Win[(size_t)(k0 + ty + 8*i) * HD + n0 + tx];
  __syncthreads();
  #pragma unroll
  for (int i = 0; i < 4; i++)
    Wt[zo + (size_t)(n0 + ty + 8*i) * HD + k0 + tx] = f2h(t[tx][ty + 8*i]);
}

__global__ __launch_bounds__(256)
void softmax_causal(const float* __restrict__ SC, u16* __restrict__ P)
{
  const int s = blockIdx.x;
  const long long zoff = (long long)blockIdx.y * SQ * SQ;
  const float* row = SC + zoff + (long long)s * SQ;
  u16* prow = P + zoff + (long long)s * SQ;

  __shared__ float buf[SQ];
  __shared__ float red[4];
  const int tid = threadIdx.x, lane = tid & 63, wid = tid >> 6;

  float m = -3.4e38f;
  for (int t = tid; t <= s; t += 256){ float v = row[t]; buf[t] = v; m = fmaxf(m, v); }
  #pragma unroll
  for (int o = 32; o; o >>= 1) m = fmaxf(m, __shfl_xor(m, o));
  if (lane == 0) red[wid] = m;
  __syncthreads();
  m = fmaxf(fmaxf(red[0], red[1]), fmaxf(red[2], red[3]));
  __syncthreads();

  float sum = 0.f;
  for (int t = tid; t <= s; t += 256){ float e = __expf(buf[t] - m); buf[t] = e; sum += e; }
  #pragma unroll
  for (int o = 32; o; o >>= 1) sum += __shfl_xor(sum, o);
  if (lane == 0) red[wid] = sum;
  __syncthreads();
  sum = red[0] + red[1] + red[2] + red[3];
  const float inv = 1.f / sum;

  const int lim = ((s >> 7) + 1) << 7;   // PV only reads keys < ceil128(s+1)
  for (int t = tid; t < lim; t += 256)
    prow[t] = (t <= s) ? f2h(buf[t] * inv) : (u16)0;
}

__global__ __launch_bounds__(256)
void layernorm_inplace(float* __restrict__ Y, const float* __restrict__ gamma,
                       const float* __restrict__ beta)
{
  float* y = Y + (long long)blockIdx.x * HD;
  const int tid = threadIdx.x, lane = tid & 63, wid = tid >> 6;
  float xv[4];
  float s = 0.f, ss = 0.f;
  #pragma unroll
  for (int i = 0; i < 4; i++){
    float v = y[tid + i * 256];
    xv[i] = v; s += v; ss += v * v;
  }
  #pragma unroll
  for (int o = 32; o; o >>= 1){ s += __shfl_xor(s, o); ss += __shfl_xor(ss, o); }
  __shared__ float r1[4], r2[4];
  if (lane == 0){ r1[wid] = s; r2[wid] = ss; }
  __syncthreads();
  s  = r1[0] + r1[1] + r1[2] + r1[3];
  ss = r2[0] + r2[1] + r2[2] + r2[3];
  const float mu   = s * (1.f / HD);
  const float var  = ss * (1.f / HD) - mu * mu;
  const float rstd = rsqrtf(var + 1e-5f);
  #pragma unroll
  for (int i = 0; i < 4; i++){
    int c = tid + i * 256;
    y[c] = (xv[i] - mu) * rstd * gamma[c] + beta[c];
  }
}

extern "C" void kernel_launch(void* const* d_in, const int* in_sizes, int n_in,
                              void* d_out, int out_size, void* d_ws, size_t ws_size,
                              hipStream_t stream)
{
  const float* x     = (const float*)d_in[0];
  const float* Wq    = (const float*)d_in[1];
  const float* bq    = (const float*)d_in[2];
  const float* Wk    = (const float*)d_in[3];
  const float* bk    = (const float*)d_in[4];
  const float* Wv    = (const float*)d_in[5];
  const float* bv    = (const float*)d_in[6];
  const float* gamma = (const float*)d_in[7];
  const float* beta  = (const float*)d_in[8];
  float* out = (float*)d_out;

  char* wsp = (char*)d_ws;
  size_t off = 0;
  auto alloc = [&](size_t bytes) -> char* {
    char* p = wsp + off;
    off = (off + bytes + 255) & ~(size_t)255;
    return p;
  };

  u16* Wt = (u16*)alloc(3ULL * HD * HD * 2);          // 6.3 MB  (transposed f16)
  u16* QK = (u16*)alloc(2ULL * NTOT * HD * 2);        // 67.1 MB (Q plane, K plane)
  u16* Vt = (u16*)alloc((size_t)NB * HD * SQ * 2);    // 33.6 MB (V transposed f16)

  // region: xh (phase A) aliased with SC/P (phase B); both dead across phases
  size_t rem = (ws_size > off) ? (ws_size - off) : 0;
  int G = (int)(rem / ((size_t)SQ * SQ * 6));
  if (G > NB) G = NB;
  if (G < 1)  G = 1;
  u16*   xh = (u16*)(wsp + off);                      // 33.5 MB
  float* SC = (float*)(wsp + off);                    // G * 16.8 MB
  u16*   P  = (u16*)(wsp + off + (size_t)G * SQ * SQ * 4);  // G * 8.4 MB

  u16* Qh = QK;
  u16* Kh = QK + (size_t)NTOT * HD;
  float* V = out;   // V fp32 lives in d_out; PV reads V[o] then overwrites o

  prep_x<<<dim3(2048), dim3(256), 0, stream>>>(x, xh);
  prep_w<<<dim3(HD/32, HD/32, 3), dim3(32, 8), 0, stream>>>(Wq, Wk, Wv, Wt);

  // QKV projection: z=0 -> Q f16, z=1 -> K f16, z=2 -> V fp32(d_out) + Vt f16
  gemm_f16<0><<<dim3(NTOT/128, HD/128, 3), 256, 0, stream>>>(
      xh, Wt, V, QK, Vt, bq, bk, bv,
      HD, HD, HD, HD,
      0LL, (long long)HD * HD, (long long)NTOT * HD);

  for (int g0 = 0; g0 < NB; g0 += G){
    int g = (G < NB - g0) ? G : (NB - g0);
    // scores: causal-compact triangular grid (136 tiles per batch)
    gemm_f16<1><<<dim3(136, 1, g), 256, 0, stream>>>(
        Qh + (size_t)g0 * SQ * HD, Kh + (size_t)g0 * SQ * HD,
        SC, nullptr, nullptr, nullptr, nullptr, nullptr,
        HD, HD, HD, SQ,
        (long long)SQ * HD, (long long)SQ * HD, (long long)SQ * SQ);
    softmax_causal<<<dim3(SQ, g), 256, 0, stream>>>(SC, P);
    // PV + residual
    gemm_f16<2><<<dim3(SQ/128, HD/128, g), 256, 0, stream>>>(
        P, Vt + (size_t)g0 * HD * SQ,
        out + (size_t)g0 * SQ * HD, nullptr, nullptr, nullptr, nullptr, nullptr,
        SQ, SQ, SQ, HD,
        (long long)SQ * SQ, (long long)HD * SQ, (long long)SQ * HD);
  }

  layernorm_inplace<<<dim3(NTOT), 256, 0, stream>>>(out, gamma, beta);
}